// Round 1
// baseline (2424.002 us; speedup 1.0000x reference)
//
#include <hip/hip_runtime.h>
#include <hip/hip_bf16.h>
#include <stdint.h>

// Problem constants
#define BATCH 256
#define SEQT  200
#define IND   128
#define HID   256
#define G3    768   // 3*HID
#define OUTD  118

typedef short  short8 __attribute__((ext_vector_type(8)));
typedef float  f32x4  __attribute__((ext_vector_type(4)));

__device__ __forceinline__ unsigned short f2bf(float x) {
    union { float f; uint32_t u; } v; v.f = x;
    uint32_t u = v.u;
    u += 0x7FFF + ((u >> 16) & 1);   // round-to-nearest-even
    return (unsigned short)(u >> 16);
}

__global__ void cvt_f32_to_bf16(const float* __restrict__ src,
                                unsigned short* __restrict__ dst, int n) {
    int i = blockIdx.x * blockDim.x + threadIdx.x;
    int stride = gridDim.x * blockDim.x;
    for (; i < n; i += stride) dst[i] = f2bf(src[i]);
}

// C[M,768] (fp32) = A[M,K](bf16) @ Bt[768,K](bf16)^T + bias[768]
// grid: M/64 blocks x 256 threads (4 waves). Wave w handles rows [mt*64+w*16, +16).
template<int K>
__global__ __launch_bounds__(256) void gemm_bf16(
    const unsigned short* __restrict__ A,
    const unsigned short* __restrict__ Bt,
    const float* __restrict__ bias,
    float* __restrict__ C)
{
    const int mt   = blockIdx.x;
    const int wave = threadIdx.x >> 6;
    const int lane = threadIdx.x & 63;
    const int col  = lane & 15;
    const int quad = lane >> 4;
    const int m0   = mt * 64 + wave * 16;
    constexpr int KS = K / 32;

    // A fragments: A[m = col][k = ks*32 + quad*8 + 0..7] -> 16B contiguous
    short8 a[KS];
    const unsigned short* arow = A + (size_t)(m0 + col) * K;
#pragma unroll
    for (int ks = 0; ks < KS; ks++)
        a[ks] = *(const short8*)(arow + ks * 32 + quad * 8);

    for (int nb = 0; nb < 6; nb++) {       // 6 x 128-col blocks = 768
        f32x4 acc[8];
#pragma unroll
        for (int nt = 0; nt < 8; nt++) acc[nt] = (f32x4)(0.0f);
#pragma unroll
        for (int ks = 0; ks < KS; ks++) {
#pragma unroll
            for (int nt = 0; nt < 8; nt++) {
                const unsigned short* bp =
                    Bt + (size_t)(nb * 128 + nt * 16 + col) * K + ks * 32 + quad * 8;
                short8 b = *(const short8*)bp;
                acc[nt] = __builtin_amdgcn_mfma_f32_16x16x32_bf16(a[ks], b, acc[nt], 0, 0, 0);
            }
        }
#pragma unroll
        for (int nt = 0; nt < 8; nt++) {
            int g = nb * 128 + nt * 16 + col;
            float bia = bias[g];
#pragma unroll
            for (int r = 0; r < 4; r++) {
                int m = m0 + quad * 4 + r;
                C[(size_t)m * G3 + g] = acc[nt][r] + bia;
            }
        }
    }
}

// GRU scan for one layer. grid: 16 WGs x 512 threads (8 waves).
// WG owns batches [wg*16, wg*16+16). Wave w owns hidden cols [w*32, w*32+32)
// (2 j-tiles) x 3 gates = 6 MFMA accumulators.
// h state: fp32 in registers (lane owns (m=quad*4+r, j=jbase+jt*16+col));
// bf16 copy in LDS feeds next step's A-fragments.
__global__ __launch_bounds__(512) void gru_scan(
    const float* __restrict__ gx,            // [B*T, 768], row = b*T + t (includes bih)
    const unsigned short* __restrict__ Whh,  // [768, 256] bf16 (B^T layout)
    const float* __restrict__ bhh,           // [768]
    unsigned short* __restrict__ h1_out,     // [B*T, 256] bf16, or nullptr
    float* __restrict__ hlast)               // [B, 256] fp32, or nullptr
{
    __shared__ unsigned short hs[16 * 264];  // 16 batches x 256 cols, stride 264 (pad)

    const int wg    = blockIdx.x;
    const int b0    = wg * 16;
    const int tid   = threadIdx.x;
    const int wave  = tid >> 6;
    const int lane  = tid & 63;
    const int col   = lane & 15;
    const int quad  = lane >> 4;
    const int jbase = wave * 32;

    // zero-init LDS h (h0 = 0)
    for (int i = tid; i < 16 * 264; i += 512) hs[i] = 0;

    float hreg[2][4];  // [jt][r]
#pragma unroll
    for (int jt = 0; jt < 2; jt++)
#pragma unroll
        for (int r = 0; r < 4; r++) hreg[jt][r] = 0.0f;

    float bh[3][2];
#pragma unroll
    for (int g3 = 0; g3 < 3; g3++)
#pragma unroll
        for (int jt = 0; jt < 2; jt++)
            bh[g3][jt] = bhh[g3 * HID + jbase + jt * 16 + col];

    __syncthreads();

    for (int t = 0; t < SEQT; t++) {
        f32x4 acc[3][2];
#pragma unroll
        for (int g3 = 0; g3 < 3; g3++)
#pragma unroll
            for (int jt = 0; jt < 2; jt++) acc[g3][jt] = (f32x4)(0.0f);

        // gh = h_bf16 @ Whh^T : K=256 in 8 steps of 32
#pragma unroll
        for (int ks = 0; ks < 8; ks++) {
            short8 a = *(const short8*)(&hs[col * 264 + ks * 32 + quad * 8]);
#pragma unroll
            for (int g3 = 0; g3 < 3; g3++)
#pragma unroll
                for (int jt = 0; jt < 2; jt++) {
                    const unsigned short* bp =
                        Whh + (size_t)(g3 * HID + jbase + jt * 16 + col) * HID + ks * 32 + quad * 8;
                    short8 b = *(const short8*)bp;
                    acc[g3][jt] = __builtin_amdgcn_mfma_f32_16x16x32_bf16(a, b, acc[g3][jt], 0, 0, 0);
                }
        }

        __syncthreads();  // all A-fragment reads done before h is overwritten

        // gate math (fp32), update h
#pragma unroll
        for (int jt = 0; jt < 2; jt++) {
            int j = jbase + jt * 16 + col;
#pragma unroll
            for (int r = 0; r < 4; r++) {
                int m = quad * 4 + r;
                size_t row = (size_t)(b0 + m) * SEQT + t;
                const float* gxp = gx + row * G3;
                float pr = gxp[j]           + acc[0][jt][r] + bh[0][jt];
                float pz = gxp[HID + j]     + acc[1][jt][r] + bh[1][jt];
                float rr = 1.0f / (1.0f + __expf(-pr));
                float zz = 1.0f / (1.0f + __expf(-pz));
                float pn = gxp[2 * HID + j] + rr * (acc[2][jt][r] + bh[2][jt]);
                float e2 = __expf(2.0f * pn);
                float nn = 1.0f - 2.0f / (e2 + 1.0f);   // tanh, inf-safe
                float hnew = (1.0f - zz) * nn + zz * hreg[jt][r];
                hreg[jt][r] = hnew;
                unsigned short hb = f2bf(hnew);
                hs[m * 264 + j] = hb;
                if (h1_out) h1_out[row * HID + j] = hb;
            }
        }

        if (hlast && t == SEQT - 1) {
#pragma unroll
            for (int jt = 0; jt < 2; jt++) {
                int j = jbase + jt * 16 + col;
#pragma unroll
                for (int r = 0; r < 4; r++)
                    hlast[(size_t)(b0 + quad * 4 + r) * HID + j] = hreg[jt][r];
            }
        }

        __syncthreads();  // new h visible before next step's reads
    }
}

// out[256,118] = hlast[256,256] @ fcW[118,256]^T + fcb
__global__ __launch_bounds__(128) void fc_kernel(
    const float* __restrict__ hlast, const float* __restrict__ W,
    const float* __restrict__ b, float* __restrict__ out)
{
    __shared__ float hsm[HID];
    int bidx = blockIdx.x;
    for (int i = threadIdx.x; i < HID; i += 128) hsm[i] = hlast[(size_t)bidx * HID + i];
    __syncthreads();
    int o = threadIdx.x;
    if (o < OUTD) {
        float acc = b[o];
        const float* wrow = W + (size_t)o * HID;
#pragma unroll 4
        for (int k = 0; k < HID; k++) acc += hsm[k] * wrow[k];
        out[(size_t)bidx * OUTD + o] = acc;
    }
}

extern "C" void kernel_launch(void* const* d_in, const int* in_sizes, int n_in,
                              void* d_out, int out_size, void* d_ws, size_t ws_size,
                              hipStream_t stream) {
    const float* x    = (const float*)d_in[0];
    const float* Wih0 = (const float*)d_in[1];
    const float* Whh0 = (const float*)d_in[2];
    const float* bih0 = (const float*)d_in[3];
    const float* bhh0 = (const float*)d_in[4];
    const float* Wih1 = (const float*)d_in[5];
    const float* Whh1 = (const float*)d_in[6];
    const float* bih1 = (const float*)d_in[7];
    const float* bhh1 = (const float*)d_in[8];
    const float* fcW  = (const float*)d_in[9];
    const float* fcb  = (const float*)d_in[10];
    float* out = (float*)d_out;

    char* ws = (char*)d_ws;
    size_t off = 0;
    auto walloc = [&](size_t bytes) {
        void* p = ws + off;
        off = (off + bytes + 255) & ~(size_t)255;
        return p;
    };

    const int M = BATCH * SEQT;                       // 51200
    float*          gxb  = (float*)         walloc((size_t)M * G3 * 4);   // 157.3 MB
    unsigned short* h1b  = (unsigned short*)walloc((size_t)M * HID * 2);  //  26.2 MB
    unsigned short* xb   = (unsigned short*)walloc((size_t)M * IND * 2);  //  13.1 MB
    unsigned short* w0b  = (unsigned short*)walloc((size_t)G3 * IND * 2);
    unsigned short* wh0b = (unsigned short*)walloc((size_t)G3 * HID * 2);
    unsigned short* w1b  = (unsigned short*)walloc((size_t)G3 * HID * 2);
    unsigned short* wh1b = (unsigned short*)walloc((size_t)G3 * HID * 2);
    float*          hlast= (float*)         walloc((size_t)BATCH * HID * 4);

    // fp32 -> bf16 conversions
    cvt_f32_to_bf16<<<2048, 256, 0, stream>>>(x,    xb,   M * IND);
    cvt_f32_to_bf16<<<64,   256, 0, stream>>>(Wih0, w0b,  G3 * IND);
    cvt_f32_to_bf16<<<96,   256, 0, stream>>>(Whh0, wh0b, G3 * HID);
    cvt_f32_to_bf16<<<96,   256, 0, stream>>>(Wih1, w1b,  G3 * HID);
    cvt_f32_to_bf16<<<96,   256, 0, stream>>>(Whh1, wh1b, G3 * HID);

    // layer 0: gx0 = x @ Wih0^T + bih0 ; scan
    gemm_bf16<IND><<<M / 64, 256, 0, stream>>>(xb, w0b, bih0, gxb);
    gru_scan<<<16, 512, 0, stream>>>(gxb, wh0b, bhh0, h1b, nullptr);

    // layer 1: gx1 = h1 @ Wih1^T + bih1 ; scan (keep only last h)
    gemm_bf16<HID><<<M / 64, 256, 0, stream>>>(h1b, w1b, bih1, gxb);
    gru_scan<<<16, 512, 0, stream>>>(gxb, wh1b, bhh1, nullptr, hlast);

    // FC head
    fc_kernel<<<BATCH, 128, 0, stream>>>(hlast, fcW, fcb, out);
}

// Round 2
// 1803.642 us; speedup vs baseline: 1.3439x; 1.3439x over previous
//
#include <hip/hip_runtime.h>
#include <hip/hip_bf16.h>
#include <stdint.h>

// Problem constants
#define BATCH 256
#define SEQT  200
#define IND   128
#define HID   256
#define G3    768   // 3*HID
#define OUTD  118

#define HSTRIDE 272  // h-state LDS row stride in shorts (16B-aligned, bank-skewed)

typedef short  short8 __attribute__((ext_vector_type(8)));
typedef float  f32x4  __attribute__((ext_vector_type(4)));

__device__ __forceinline__ unsigned short f2bf(float x) {
    union { float f; uint32_t u; } v; v.f = x;
    uint32_t u = v.u;
    u += 0x7FFF + ((u >> 16) & 1);   // round-to-nearest-even
    return (unsigned short)(u >> 16);
}

__global__ void cvt_f32_to_bf16(const float* __restrict__ src,
                                unsigned short* __restrict__ dst, int n) {
    int i = blockIdx.x * blockDim.x + threadIdx.x;
    int stride = gridDim.x * blockDim.x;
    for (; i < n; i += stride) dst[i] = f2bf(src[i]);
}

// C[M,768] (fp32) = A[M,K](bf16) @ Bt[768,K](bf16)^T + bias[768]
template<int K>
__global__ __launch_bounds__(256) void gemm_bf16(
    const unsigned short* __restrict__ A,
    const unsigned short* __restrict__ Bt,
    const float* __restrict__ bias,
    float* __restrict__ C)
{
    const int mt   = blockIdx.x;
    const int wave = threadIdx.x >> 6;
    const int lane = threadIdx.x & 63;
    const int col  = lane & 15;
    const int quad = lane >> 4;
    const int m0   = mt * 64 + wave * 16;
    constexpr int KS = K / 32;

    short8 a[KS];
    const unsigned short* arow = A + (size_t)(m0 + col) * K;
#pragma unroll
    for (int ks = 0; ks < KS; ks++)
        a[ks] = *(const short8*)(arow + ks * 32 + quad * 8);

    for (int nb = 0; nb < 6; nb++) {
        f32x4 acc[8];
#pragma unroll
        for (int nt = 0; nt < 8; nt++) acc[nt] = (f32x4)(0.0f);
#pragma unroll
        for (int ks = 0; ks < KS; ks++) {
#pragma unroll
            for (int nt = 0; nt < 8; nt++) {
                const unsigned short* bp =
                    Bt + (size_t)(nb * 128 + nt * 16 + col) * K + ks * 32 + quad * 8;
                short8 b = *(const short8*)bp;
                acc[nt] = __builtin_amdgcn_mfma_f32_16x16x32_bf16(a[ks], b, acc[nt], 0, 0, 0);
            }
        }
#pragma unroll
        for (int nt = 0; nt < 8; nt++) {
            int g = nb * 128 + nt * 16 + col;
            float bia = bias[g];
#pragma unroll
            for (int r = 0; r < 4; r++) {
                int m = m0 + quad * 4 + r;
                C[(size_t)m * G3 + g] = acc[nt][r] + bia;
            }
        }
    }
}

// GRU scan, weight-resident version.
// grid: 16 WGs x 512 threads (8 waves). WG owns batches [wg*16, +16).
// Wave w owns hidden cols [w*32, +32) (2 j-tiles) x 3 gates.
// r,z gate Whh slices: VGPR-resident B-fragments (128 regs/lane).
// n  gate Whh slices: LDS-resident (128KB), contiguous per-lane frags.
// h state: fp32 in regs + bf16 double-buffered in LDS -> 1 barrier/step.
__global__ __launch_bounds__(512, 2) void gru_scan(
    const float* __restrict__ gx,            // [B*T, 768], row = b*T + t (includes bih)
    const unsigned short* __restrict__ Whh,  // [768, 256] bf16
    const float* __restrict__ bhh,           // [768]
    unsigned short* __restrict__ h1_out,     // [B*T, 256] bf16, or nullptr
    float* __restrict__ hlast)               // [B, 256] fp32, or nullptr
{
    __shared__ unsigned short hs[2][16 * HSTRIDE];        // 17,408 B
    __shared__ unsigned short wn[8 * 2 * 8 * 512];        // 131,072 B (n-gate weights)

    const int wg    = blockIdx.x;
    const int b0    = wg * 16;
    const int tid   = threadIdx.x;
    const int wave  = tid >> 6;
    const int lane  = tid & 63;
    const int col   = lane & 15;
    const int quad  = lane >> 4;
    const int jbase = wave * 32;

    // ---- load r,z weights into registers (B-fragment layout) ----
    short8 wrz[2][2][8];   // [gate][jt][ks]
#pragma unroll
    for (int g = 0; g < 2; g++)
#pragma unroll
        for (int jt = 0; jt < 2; jt++)
#pragma unroll
            for (int ks = 0; ks < 8; ks++)
                wrz[g][jt][ks] = *(const short8*)(
                    Whh + (size_t)(g * HID + jbase + jt * 16 + col) * HID + ks * 32 + quad * 8);

    // ---- stage n-gate weights into LDS in per-lane-contiguous frag order ----
#pragma unroll
    for (int jt = 0; jt < 2; jt++)
#pragma unroll
        for (int ks = 0; ks < 8; ks++) {
            const unsigned short* src =
                Whh + (size_t)(2 * HID + jbase + jt * 16 + col) * HID + ks * 32 + quad * 8;
            *(short8*)&wn[(((wave * 2 + jt) * 8 + ks) * 512) + lane * 8] = *(const short8*)src;
        }

    // ---- init h ----
    for (int i = tid; i < 16 * HSTRIDE; i += 512) hs[0][i] = 0;

    float hreg[2][4];
#pragma unroll
    for (int jt = 0; jt < 2; jt++)
#pragma unroll
        for (int r = 0; r < 4; r++) hreg[jt][r] = 0.0f;

    float bh[3][2];
#pragma unroll
    for (int g3 = 0; g3 < 3; g3++)
#pragma unroll
        for (int jt = 0; jt < 2; jt++)
            bh[g3][jt] = bhh[g3 * HID + jbase + jt * 16 + col];

    // per-row gx / h1_out pointers (advance by one t per step)
    const float* gxp[4];
    size_t h1off[4];
#pragma unroll
    for (int r = 0; r < 4; r++) {
        size_t row = (size_t)(b0 + quad * 4 + r) * SEQT;  // t = 0
        gxp[r]   = gx + row * G3;
        h1off[r] = row * HID;
    }

    __syncthreads();

    for (int t = 0; t < SEQT; t++) {
        const int cur = t & 1;
        const int nxt = cur ^ 1;

        f32x4 acc[3][2];
#pragma unroll
        for (int g3 = 0; g3 < 3; g3++)
#pragma unroll
            for (int jt = 0; jt < 2; jt++) acc[g3][jt] = (f32x4)(0.0f);

#pragma unroll
        for (int ks = 0; ks < 8; ks++) {
            short8 a = *(const short8*)(&hs[cur][col * HSTRIDE + ks * 32 + quad * 8]);
#pragma unroll
            for (int jt = 0; jt < 2; jt++) {
                acc[0][jt] = __builtin_amdgcn_mfma_f32_16x16x32_bf16(a, wrz[0][jt][ks], acc[0][jt], 0, 0, 0);
                acc[1][jt] = __builtin_amdgcn_mfma_f32_16x16x32_bf16(a, wrz[1][jt][ks], acc[1][jt], 0, 0, 0);
                short8 bn = *(const short8*)&wn[(((wave * 2 + jt) * 8 + ks) * 512) + lane * 8];
                acc[2][jt] = __builtin_amdgcn_mfma_f32_16x16x32_bf16(a, bn, acc[2][jt], 0, 0, 0);
            }
        }

        // gate math (fp32), update h, write next LDS buffer
#pragma unroll
        for (int jt = 0; jt < 2; jt++) {
            int j = jbase + jt * 16 + col;
#pragma unroll
            for (int r = 0; r < 4; r++) {
                int m = quad * 4 + r;
                const float* gp = gxp[r];
                float pr = gp[j]           + acc[0][jt][r] + bh[0][jt];
                float pz = gp[HID + j]     + acc[1][jt][r] + bh[1][jt];
                float rr = 1.0f / (1.0f + __expf(-pr));
                float zz = 1.0f / (1.0f + __expf(-pz));
                float pn = gp[2 * HID + j] + rr * (acc[2][jt][r] + bh[2][jt]);
                float e2 = __expf(2.0f * pn);
                float nn = 1.0f - 2.0f / (e2 + 1.0f);   // tanh, inf-safe
                float hnew = (1.0f - zz) * nn + zz * hreg[jt][r];
                hreg[jt][r] = hnew;
                unsigned short hb = f2bf(hnew);
                hs[nxt][m * HSTRIDE + j] = hb;
                if (h1_out) h1_out[h1off[r] + j] = hb;
            }
        }

#pragma unroll
        for (int r = 0; r < 4; r++) { gxp[r] += G3; h1off[r] += HID; }

        if (hlast && t == SEQT - 1) {
#pragma unroll
            for (int jt = 0; jt < 2; jt++) {
                int j = jbase + jt * 16 + col;
#pragma unroll
                for (int r = 0; r < 4; r++)
                    hlast[(size_t)(b0 + quad * 4 + r) * HID + j] = hreg[jt][r];
            }
        }

        __syncthreads();  // next-buffer writes visible before next step's reads
    }
}

// out[256,118] = hlast[256,256] @ fcW[118,256]^T + fcb
__global__ __launch_bounds__(128) void fc_kernel(
    const float* __restrict__ hlast, const float* __restrict__ W,
    const float* __restrict__ b, float* __restrict__ out)
{
    __shared__ float hsm[HID];
    int bidx = blockIdx.x;
    for (int i = threadIdx.x; i < HID; i += 128) hsm[i] = hlast[(size_t)bidx * HID + i];
    __syncthreads();
    int o = threadIdx.x;
    if (o < OUTD) {
        float acc = b[o];
        const float* wrow = W + (size_t)o * HID;
#pragma unroll 4
        for (int k = 0; k < HID; k++) acc += hsm[k] * wrow[k];
        out[(size_t)bidx * OUTD + o] = acc;
    }
}

extern "C" void kernel_launch(void* const* d_in, const int* in_sizes, int n_in,
                              void* d_out, int out_size, void* d_ws, size_t ws_size,
                              hipStream_t stream) {
    const float* x    = (const float*)d_in[0];
    const float* Wih0 = (const float*)d_in[1];
    const float* Whh0 = (const float*)d_in[2];
    const float* bih0 = (const float*)d_in[3];
    const float* bhh0 = (const float*)d_in[4];
    const float* Wih1 = (const float*)d_in[5];
    const float* Whh1 = (const float*)d_in[6];
    const float* bih1 = (const float*)d_in[7];
    const float* bhh1 = (const float*)d_in[8];
    const float* fcW  = (const float*)d_in[9];
    const float* fcb  = (const float*)d_in[10];
    float* out = (float*)d_out;

    char* ws = (char*)d_ws;
    size_t off = 0;
    auto walloc = [&](size_t bytes) {
        void* p = ws + off;
        off = (off + bytes + 255) & ~(size_t)255;
        return p;
    };

    const int M = BATCH * SEQT;                       // 51200
    float*          gxb  = (float*)         walloc((size_t)M * G3 * 4);   // 157.3 MB
    unsigned short* h1b  = (unsigned short*)walloc((size_t)M * HID * 2);  //  26.2 MB
    unsigned short* xb   = (unsigned short*)walloc((size_t)M * IND * 2);  //  13.1 MB
    unsigned short* w0b  = (unsigned short*)walloc((size_t)G3 * IND * 2);
    unsigned short* wh0b = (unsigned short*)walloc((size_t)G3 * HID * 2);
    unsigned short* w1b  = (unsigned short*)walloc((size_t)G3 * HID * 2);
    unsigned short* wh1b = (unsigned short*)walloc((size_t)G3 * HID * 2);
    float*          hlast= (float*)         walloc((size_t)BATCH * HID * 4);

    cvt_f32_to_bf16<<<2048, 256, 0, stream>>>(x,    xb,   M * IND);
    cvt_f32_to_bf16<<<64,   256, 0, stream>>>(Wih0, w0b,  G3 * IND);
    cvt_f32_to_bf16<<<96,   256, 0, stream>>>(Whh0, wh0b, G3 * HID);
    cvt_f32_to_bf16<<<96,   256, 0, stream>>>(Wih1, w1b,  G3 * HID);
    cvt_f32_to_bf16<<<96,   256, 0, stream>>>(Whh1, wh1b, G3 * HID);

    // layer 0
    gemm_bf16<IND><<<M / 64, 256, 0, stream>>>(xb, w0b, bih0, gxb);
    gru_scan<<<16, 512, 0, stream>>>(gxb, wh0b, bhh0, h1b, nullptr);

    // layer 1
    gemm_bf16<HID><<<M / 64, 256, 0, stream>>>(h1b, w1b, bih1, gxb);
    gru_scan<<<16, 512, 0, stream>>>(gxb, wh1b, bhh1, nullptr, hlast);

    // FC head
    fc_kernel<<<BATCH, 128, 0, stream>>>(hlast, fcW, fcb, out);
}

// Round 3
// 1185.020 us; speedup vs baseline: 2.0455x; 1.5220x over previous
//
#include <hip/hip_runtime.h>
#include <hip/hip_bf16.h>
#include <stdint.h>

// Problem constants
#define BATCH 256
#define SEQT  200
#define IND   128
#define HID   256
#define G3    768   // 3*HID
#define OUTD  118

#define HSTRIDE 272  // h-state LDS row stride in shorts
#define W0SZ (G3*IND)
#define WHSZ (G3*HID)

typedef short  short8 __attribute__((ext_vector_type(8)));
typedef float  f32x4  __attribute__((ext_vector_type(4)));

__device__ __forceinline__ unsigned short f2bf(float x) {
    union { float f; uint32_t u; } v; v.f = x;
    uint32_t u = v.u;
    u += 0x7FFF + ((u >> 16) & 1);   // round-to-nearest-even
    return (unsigned short)(u >> 16);
}

// One fused conversion kernel for all four weight matrices.
__global__ void cvt_weights(const float* __restrict__ w0,  const float* __restrict__ wh0,
                            const float* __restrict__ w1,  const float* __restrict__ wh1,
                            unsigned short* __restrict__ o0,  unsigned short* __restrict__ oh0,
                            unsigned short* __restrict__ o1,  unsigned short* __restrict__ oh1) {
    int i = blockIdx.x * blockDim.x + threadIdx.x;
    const int n = W0SZ + 3 * WHSZ;
    int stride = gridDim.x * blockDim.x;
    for (; i < n; i += stride) {
        int j = i;
        if (j < W0SZ) { o0[j] = f2bf(w0[j]); continue; }
        j -= W0SZ;
        if (j < WHSZ) { oh0[j] = f2bf(wh0[j]); continue; }
        j -= WHSZ;
        if (j < WHSZ) { o1[j] = f2bf(w1[j]); continue; }
        j -= WHSZ;
        oh1[j] = f2bf(wh1[j]);
    }
}

// bc = bih + bhh for r,z gates (j < 512); bc = bih for n gate. Both layers.
__global__ void combine_bias(const float* __restrict__ bih0, const float* __restrict__ bhh0,
                             const float* __restrict__ bih1, const float* __restrict__ bhh1,
                             float* __restrict__ bc0, float* __restrict__ bc1) {
    int i = blockIdx.x * blockDim.x + threadIdx.x;
    if (i < G3) bc0[i] = bih0[i] + (i < 2 * HID ? bhh0[i] : 0.0f);
    else if (i < 2 * G3) {
        int j = i - G3;
        bc1[j] = bih1[j] + (j < 2 * HID ? bhh1[j] : 0.0f);
    }
}

// C[M,768] (fp32) = A[M,K] @ Bt[768,K](bf16)^T + bias[768]
// AF32: A is fp32 (converted to bf16 in-register); else A is bf16.
template<int K, bool AF32>
__global__ __launch_bounds__(256) void gemm_bf16(
    const void* __restrict__ Av,
    const unsigned short* __restrict__ Bt,
    const float* __restrict__ bias,
    float* __restrict__ C)
{
    const int mt   = blockIdx.x;
    const int wave = threadIdx.x >> 6;
    const int lane = threadIdx.x & 63;
    const int col  = lane & 15;
    const int quad = lane >> 4;
    const int m0   = mt * 64 + wave * 16;
    constexpr int KS = K / 32;

    short8 a[KS];
    if constexpr (AF32) {
        const float* arow = (const float*)Av + (size_t)(m0 + col) * K;
#pragma unroll
        for (int ks = 0; ks < KS; ks++) {
            f32x4 lo = *(const f32x4*)(arow + ks * 32 + quad * 8);
            f32x4 hi = *(const f32x4*)(arow + ks * 32 + quad * 8 + 4);
#pragma unroll
            for (int e = 0; e < 4; e++) {
                a[ks][e]     = (short)f2bf(lo[e]);
                a[ks][e + 4] = (short)f2bf(hi[e]);
            }
        }
    } else {
        const unsigned short* arow = (const unsigned short*)Av + (size_t)(m0 + col) * K;
#pragma unroll
        for (int ks = 0; ks < KS; ks++)
            a[ks] = *(const short8*)(arow + ks * 32 + quad * 8);
    }

    for (int nb = 0; nb < 6; nb++) {
        f32x4 acc[8];
#pragma unroll
        for (int nt = 0; nt < 8; nt++) acc[nt] = (f32x4)(0.0f);
#pragma unroll
        for (int ks = 0; ks < KS; ks++) {
#pragma unroll
            for (int nt = 0; nt < 8; nt++) {
                const unsigned short* bp =
                    Bt + (size_t)(nb * 128 + nt * 16 + col) * K + ks * 32 + quad * 8;
                short8 b = *(const short8*)bp;
                acc[nt] = __builtin_amdgcn_mfma_f32_16x16x32_bf16(a[ks], b, acc[nt], 0, 0, 0);
            }
        }
#pragma unroll
        for (int nt = 0; nt < 8; nt++) {
            int g = nb * 128 + nt * 16 + col;
            float bia = bias[g];
#pragma unroll
            for (int r = 0; r < 4; r++) {
                int m = m0 + quad * 4 + r;
                C[(size_t)m * G3 + g] = acc[nt][r] + bia;
            }
        }
    }
}

// GRU scan. 16 WGs x 512 threads. WG owns batches [wg*16,+16); wave owns 32 cols.
// r,z Whh: VGPR-pinned (128 regs/lane, asm-forced). n Whh: LDS (128KB).
// h: fp32 regs + bf16 double-buffered LDS; 1 barrier/step.
// Order per step: prefetch gx -> MFMA(jt0) -> MFMA(jt1) -> gates(jt0) -> gates(jt1)
// so jt1's MFMAs execute under jt0's VALU.
__global__ __launch_bounds__(512, 2) void gru_scan(
    const float* __restrict__ gx,            // [B*T,768], row=b*T+t (bih+bhh_rz folded)
    const unsigned short* __restrict__ Whh,  // [768,256] bf16
    const float* __restrict__ bhh,           // [768] (only n-part used)
    unsigned short* __restrict__ h1_out,     // [B*T,256] bf16 or nullptr
    float* __restrict__ hlast)               // [B,256] fp32 or nullptr
{
    __shared__ unsigned short hs[2][16 * HSTRIDE];   // 17,408 B
    __shared__ unsigned short wn[8 * 2 * 8 * 512];   // 131,072 B

    const int b0    = blockIdx.x * 16;
    const int tid   = threadIdx.x;
    const int wave  = tid >> 6;
    const int lane  = tid & 63;
    const int col   = lane & 15;
    const int quad  = lane >> 4;
    const int jbase = wave * 32;

    // r,z weights -> registers (raw bf16 bits held in float regs)
    float wrz[2][2][8][4];
#pragma unroll
    for (int g = 0; g < 2; g++)
#pragma unroll
        for (int jt = 0; jt < 2; jt++)
#pragma unroll
            for (int ks = 0; ks < 8; ks++) {
                f32x4 tv = *(const f32x4*)(
                    Whh + (size_t)(g * HID + jbase + jt * 16 + col) * HID + ks * 32 + quad * 8);
#pragma unroll
                for (int e = 0; e < 4; e++) wrz[g][jt][ks][e] = tv[e];
            }

    // n weights -> LDS, per-lane-contiguous fragment order
#pragma unroll
    for (int jt = 0; jt < 2; jt++)
#pragma unroll
        for (int ks = 0; ks < 8; ks++)
            *(short8*)&wn[(((wave * 2 + jt) * 8 + ks) << 9) + lane * 8] =
                *(const short8*)(Whh + (size_t)(2 * HID + jbase + jt * 16 + col) * HID + ks * 32 + quad * 8);

    for (int i = tid; i < 16 * HSTRIDE; i += 512) hs[0][i] = 0;

    float hreg[2][4] = {};
    float bhn[2];
#pragma unroll
    for (int jt = 0; jt < 2; jt++) bhn[jt] = bhh[2 * HID + jbase + jt * 16 + col];

    const float* gp[4];
    size_t hoff[4];
    int haddr[4];
#pragma unroll
    for (int r = 0; r < 4; r++) {
        size_t row = (size_t)(b0 + quad * 4 + r) * SEQT;
        gp[r]    = gx + row * G3 + jbase + col;
        hoff[r]  = row * HID + jbase + col;
        haddr[r] = (quad * 4 + r) * HSTRIDE + jbase + col;
    }

    __syncthreads();

    for (int t = 0; t < SEQT; t++) {
        const unsigned short* hc = hs[t & 1];
        unsigned short*       hn = hs[(t & 1) ^ 1];

        // Pin weight regs: opaque redefinition each iter -> compiler cannot
        // rematerialize from memory, must keep 128 VGPRs resident.
#pragma unroll
        for (int g = 0; g < 2; g++)
#pragma unroll
            for (int jt = 0; jt < 2; jt++)
#pragma unroll
                for (int ks = 0; ks < 8; ks++)
#pragma unroll
                    for (int e = 0; e < 4; e++)
                        asm volatile("" : "+v"(wrz[g][jt][ks][e]));

        // prefetch gx (r,z) — latency hides under MFMA phase
        float g_r[2][4], g_z[2][4], g_n[2][4];
#pragma unroll
        for (int jt = 0; jt < 2; jt++)
#pragma unroll
            for (int r = 0; r < 4; r++) {
                g_r[jt][r] = gp[r][jt * 16];
                g_z[jt][r] = gp[r][HID + jt * 16];
            }

        f32x4 acc[3][2];
#pragma unroll
        for (int g = 0; g < 3; g++)
#pragma unroll
            for (int jt = 0; jt < 2; jt++) acc[g][jt] = (f32x4)(0.0f);

        // MFMA, jt = 0
#pragma unroll
        for (int ks = 0; ks < 8; ks++) {
            short8 a = *(const short8*)(&hc[col * HSTRIDE + ks * 32 + quad * 8]);
            f32x4 w0v = { wrz[0][0][ks][0], wrz[0][0][ks][1], wrz[0][0][ks][2], wrz[0][0][ks][3] };
            f32x4 w1v = { wrz[1][0][ks][0], wrz[1][0][ks][1], wrz[1][0][ks][2], wrz[1][0][ks][3] };
            acc[0][0] = __builtin_amdgcn_mfma_f32_16x16x32_bf16(a, __builtin_bit_cast(short8, w0v), acc[0][0], 0, 0, 0);
            acc[1][0] = __builtin_amdgcn_mfma_f32_16x16x32_bf16(a, __builtin_bit_cast(short8, w1v), acc[1][0], 0, 0, 0);
            short8 bn = *(const short8*)&wn[((wave * 16 + ks) << 9) + lane * 8];
            acc[2][0] = __builtin_amdgcn_mfma_f32_16x16x32_bf16(a, bn, acc[2][0], 0, 0, 0);
        }

        // prefetch gx (n) — hides under jt1 MFMAs
#pragma unroll
        for (int jt = 0; jt < 2; jt++)
#pragma unroll
            for (int r = 0; r < 4; r++)
                g_n[jt][r] = gp[r][2 * HID + jt * 16];

        // MFMA, jt = 1
#pragma unroll
        for (int ks = 0; ks < 8; ks++) {
            short8 a = *(const short8*)(&hc[col * HSTRIDE + ks * 32 + quad * 8]);
            f32x4 w0v = { wrz[0][1][ks][0], wrz[0][1][ks][1], wrz[0][1][ks][2], wrz[0][1][ks][3] };
            f32x4 w1v = { wrz[1][1][ks][0], wrz[1][1][ks][1], wrz[1][1][ks][2], wrz[1][1][ks][3] };
            acc[0][1] = __builtin_amdgcn_mfma_f32_16x16x32_bf16(a, __builtin_bit_cast(short8, w0v), acc[0][1], 0, 0, 0);
            acc[1][1] = __builtin_amdgcn_mfma_f32_16x16x32_bf16(a, __builtin_bit_cast(short8, w1v), acc[1][1], 0, 0, 0);
            short8 bn = *(const short8*)&wn[(((wave * 2 + 1) * 8 + ks) << 9) + lane * 8];
            acc[2][1] = __builtin_amdgcn_mfma_f32_16x16x32_bf16(a, bn, acc[2][1], 0, 0, 0);
        }

        // gate math: jt0 first (its MFMAs retired; jt1's still in the pipe)
#pragma unroll
        for (int jt = 0; jt < 2; jt++) {
#pragma unroll
            for (int r = 0; r < 4; r++) {
                float pr = g_r[jt][r] + acc[0][jt][r];
                float pz = g_z[jt][r] + acc[1][jt][r];
                float rr = __builtin_amdgcn_rcpf(1.0f + __expf(-pr));
                float zz = __builtin_amdgcn_rcpf(1.0f + __expf(-pz));
                float pn = g_n[jt][r] + rr * (acc[2][jt][r] + bhn[jt]);
                float nn = 1.0f - 2.0f * __builtin_amdgcn_rcpf(__expf(2.0f * pn) + 1.0f);
                float hnew = nn + zz * (hreg[jt][r] - nn);
                hreg[jt][r] = hnew;
                unsigned short hb = f2bf(hnew);
                hn[haddr[r] + jt * 16] = hb;
                if (h1_out) h1_out[hoff[r] + jt * 16] = hb;
            }
        }

#pragma unroll
        for (int r = 0; r < 4; r++) { gp[r] += G3; hoff[r] += HID; }

        if (hlast && t == SEQT - 1) {
#pragma unroll
            for (int jt = 0; jt < 2; jt++) {
                int j = jbase + jt * 16 + col;
#pragma unroll
                for (int r = 0; r < 4; r++)
                    hlast[(size_t)(b0 + quad * 4 + r) * HID + j] = hreg[jt][r];
            }
        }

        __syncthreads();
    }
}

// out[256,118] = hlast[256,256] @ fcW[118,256]^T + fcb
__global__ __launch_bounds__(128) void fc_kernel(
    const float* __restrict__ hlast, const float* __restrict__ W,
    const float* __restrict__ b, float* __restrict__ out)
{
    __shared__ float hsm[HID];
    int bidx = blockIdx.x;
    for (int i = threadIdx.x; i < HID; i += 128) hsm[i] = hlast[(size_t)bidx * HID + i];
    __syncthreads();
    int o = threadIdx.x;
    if (o < OUTD) {
        float acc = b[o];
        const float* wrow = W + (size_t)o * HID;
#pragma unroll 4
        for (int k = 0; k < HID; k++) acc += hsm[k] * wrow[k];
        out[(size_t)bidx * OUTD + o] = acc;
    }
}

extern "C" void kernel_launch(void* const* d_in, const int* in_sizes, int n_in,
                              void* d_out, int out_size, void* d_ws, size_t ws_size,
                              hipStream_t stream) {
    const float* x    = (const float*)d_in[0];
    const float* Wih0 = (const float*)d_in[1];
    const float* Whh0 = (const float*)d_in[2];
    const float* bih0 = (const float*)d_in[3];
    const float* bhh0 = (const float*)d_in[4];
    const float* Wih1 = (const float*)d_in[5];
    const float* Whh1 = (const float*)d_in[6];
    const float* bih1 = (const float*)d_in[7];
    const float* bhh1 = (const float*)d_in[8];
    const float* fcW  = (const float*)d_in[9];
    const float* fcb  = (const float*)d_in[10];
    float* out = (float*)d_out;

    char* ws = (char*)d_ws;
    size_t off = 0;
    auto walloc = [&](size_t bytes) {
        void* p = ws + off;
        off = (off + bytes + 255) & ~(size_t)255;
        return p;
    };

    const int M = BATCH * SEQT;                       // 51200
    float*          gxb  = (float*)         walloc((size_t)M * G3 * 4);   // 157.3 MB
    unsigned short* h1b  = (unsigned short*)walloc((size_t)M * HID * 2);  //  26.2 MB
    unsigned short* w0b  = (unsigned short*)walloc((size_t)W0SZ * 2);
    unsigned short* wh0b = (unsigned short*)walloc((size_t)WHSZ * 2);
    unsigned short* w1b  = (unsigned short*)walloc((size_t)WHSZ * 2);
    unsigned short* wh1b = (unsigned short*)walloc((size_t)WHSZ * 2);
    float*          bc0  = (float*)         walloc(G3 * 4);
    float*          bc1  = (float*)         walloc(G3 * 4);
    float*          hlast= (float*)         walloc((size_t)BATCH * HID * 4);

    cvt_weights <<<2688, 256, 0, stream>>>(Wih0, Whh0, Wih1, Whh1, w0b, wh0b, w1b, wh1b);
    combine_bias<<<6,    256, 0, stream>>>(bih0, bhh0, bih1, bhh1, bc0, bc1);

    // layer 0 (A = x, fp32 read + in-register cvt)
    gemm_bf16<IND, true ><<<M / 64, 256, 0, stream>>>(x, w0b, bc0, gxb);
    gru_scan<<<16, 512, 0, stream>>>(gxb, wh0b, bhh0, h1b, nullptr);

    // layer 1
    gemm_bf16<HID, false><<<M / 64, 256, 0, stream>>>(h1b, w1b, bc1, gxb);
    gru_scan<<<16, 512, 0, stream>>>(gxb, wh1b, bhh1, nullptr, hlast);

    fc_kernel<<<BATCH, 128, 0, stream>>>(hlast, fcW, fcb, out);
}

// Round 4
// 1178.384 us; speedup vs baseline: 2.0571x; 1.0056x over previous
//
#include <hip/hip_runtime.h>
#include <hip/hip_bf16.h>
#include <stdint.h>

// Problem constants
#define BATCH 256
#define SEQT  200
#define IND   128
#define HID   256
#define G3    768   // 3*HID
#define OUTD  118

#define HSTRIDE 280  // h-state LDS row stride in shorts (16B aligned; 4-way max conflict)
#define W0SZ (G3*IND)
#define WHSZ (G3*HID)

#define LOG2E  1.44269504f
#define NLOG2E (-1.44269504f)
#define LOG2E2 2.88539008f

typedef short  short8 __attribute__((ext_vector_type(8)));
typedef float  f32x4  __attribute__((ext_vector_type(4)));

__device__ __forceinline__ float exp2fast(float x) {
#if __has_builtin(__builtin_amdgcn_exp2f)
    return __builtin_amdgcn_exp2f(x);
#else
    return exp2f(x);
#endif
}

__device__ __forceinline__ unsigned short f2bf(float x) {
    union { float f; uint32_t u; } v; v.f = x;
    uint32_t u = v.u;
    u += 0x7FFF + ((u >> 16) & 1);   // round-to-nearest-even
    return (unsigned short)(u >> 16);
}

// One fused conversion kernel for all four weight matrices.
__global__ void cvt_weights(const float* __restrict__ w0,  const float* __restrict__ wh0,
                            const float* __restrict__ w1,  const float* __restrict__ wh1,
                            unsigned short* __restrict__ o0,  unsigned short* __restrict__ oh0,
                            unsigned short* __restrict__ o1,  unsigned short* __restrict__ oh1) {
    int i = blockIdx.x * blockDim.x + threadIdx.x;
    const int n = W0SZ + 3 * WHSZ;
    int stride = gridDim.x * blockDim.x;
    for (; i < n; i += stride) {
        int j = i;
        if (j < W0SZ) { o0[j] = f2bf(w0[j]); continue; }
        j -= W0SZ;
        if (j < WHSZ) { oh0[j] = f2bf(wh0[j]); continue; }
        j -= WHSZ;
        if (j < WHSZ) { o1[j] = f2bf(w1[j]); continue; }
        j -= WHSZ;
        oh1[j] = f2bf(wh1[j]);
    }
}

// bc = bih + bhh for r,z gates (j < 512); bc = bih for n gate. Both layers.
__global__ void combine_bias(const float* __restrict__ bih0, const float* __restrict__ bhh0,
                             const float* __restrict__ bih1, const float* __restrict__ bhh1,
                             float* __restrict__ bc0, float* __restrict__ bc1) {
    int i = blockIdx.x * blockDim.x + threadIdx.x;
    if (i < G3) bc0[i] = bih0[i] + (i < 2 * HID ? bhh0[i] : 0.0f);
    else if (i < 2 * G3) {
        int j = i - G3;
        bc1[j] = bih1[j] + (j < 2 * HID ? bhh1[j] : 0.0f);
    }
}

// C[M,768] = scale[g] * (A[M,K] @ Bt[768,K]^T + bias[g])
// scale = -log2e for r,z gates; +2*log2e for n gate (pre-scales the exp2 args
// consumed by gru_scan).
template<int K, bool AF32>
__global__ __launch_bounds__(256) void gemm_bf16(
    const void* __restrict__ Av,
    const unsigned short* __restrict__ Bt,
    const float* __restrict__ bias,
    float* __restrict__ C)
{
    const int mt   = blockIdx.x;
    const int wave = threadIdx.x >> 6;
    const int lane = threadIdx.x & 63;
    const int col  = lane & 15;
    const int quad = lane >> 4;
    const int m0   = mt * 64 + wave * 16;
    constexpr int KS = K / 32;

    short8 a[KS];
    if constexpr (AF32) {
        const float* arow = (const float*)Av + (size_t)(m0 + col) * K;
#pragma unroll
        for (int ks = 0; ks < KS; ks++) {
            f32x4 lo = *(const f32x4*)(arow + ks * 32 + quad * 8);
            f32x4 hi = *(const f32x4*)(arow + ks * 32 + quad * 8 + 4);
#pragma unroll
            for (int e = 0; e < 4; e++) {
                a[ks][e]     = (short)f2bf(lo[e]);
                a[ks][e + 4] = (short)f2bf(hi[e]);
            }
        }
    } else {
        const unsigned short* arow = (const unsigned short*)Av + (size_t)(m0 + col) * K;
#pragma unroll
        for (int ks = 0; ks < KS; ks++)
            a[ks] = *(const short8*)(arow + ks * 32 + quad * 8);
    }

#pragma unroll
    for (int nb = 0; nb < 6; nb++) {
        const float scl = (nb < 4) ? NLOG2E : LOG2E2;
        f32x4 acc[8];
#pragma unroll
        for (int nt = 0; nt < 8; nt++) acc[nt] = (f32x4)(0.0f);
#pragma unroll
        for (int ks = 0; ks < KS; ks++) {
#pragma unroll
            for (int nt = 0; nt < 8; nt++) {
                const unsigned short* bp =
                    Bt + (size_t)(nb * 128 + nt * 16 + col) * K + ks * 32 + quad * 8;
                short8 b = *(const short8*)bp;
                acc[nt] = __builtin_amdgcn_mfma_f32_16x16x32_bf16(a[ks], b, acc[nt], 0, 0, 0);
            }
        }
#pragma unroll
        for (int nt = 0; nt < 8; nt++) {
            int g = nb * 128 + nt * 16 + col;
            float bia = bias[g];
#pragma unroll
            for (int r = 0; r < 4; r++) {
                int m = m0 + quad * 4 + r;
                C[(size_t)m * G3 + g] = (acc[nt][r] + bia) * scl;
            }
        }
    }
}

// GRU scan. 16 WGs x 1024 threads (16 waves, 4/SIMD). WG owns batches [wg*16,+16);
// wave owns ONE 16-col j-slice x 3 gates (3 MFMA acc chains).
// r,z Whh: VGPR-pinned (64 regs/lane). n Whh: LDS (128KB).
// gx: software-pipelined one step ahead (loads issued at t, consumed at t+1).
// h: fp32 regs + bf16 double-buffered LDS; 1 barrier/step.
__global__ __launch_bounds__(1024) void gru_scan(
    const float* __restrict__ gx,            // [B*T,768] pre-scaled exp2 args
    const unsigned short* __restrict__ Whh,  // [768,256] bf16
    const float* __restrict__ bhh,           // [768] (only n-part used)
    unsigned short* __restrict__ h1_out,     // [B*T,256] bf16 or nullptr
    float* __restrict__ hlast)               // [B,256] fp32 or nullptr
{
    __shared__ unsigned short hs[2][16 * HSTRIDE];   // 17,920 B
    __shared__ unsigned short wn[16 * 8 * 512];      // 131,072 B

    const int b0    = blockIdx.x * 16;
    const int tid   = threadIdx.x;
    const int wave  = tid >> 6;
    const int lane  = tid & 63;
    const int col   = lane & 15;
    const int quad  = lane >> 4;
    const int j     = wave * 16 + col;

    // r,z weights -> registers (raw bf16 bits in float regs; 64 VGPRs)
    float wrz[2][8][4];
#pragma unroll
    for (int g = 0; g < 2; g++)
#pragma unroll
        for (int ks = 0; ks < 8; ks++) {
            f32x4 tv = *(const f32x4*)(
                Whh + (size_t)(g * HID + j) * HID + ks * 32 + quad * 8);
#pragma unroll
            for (int e = 0; e < 4; e++) wrz[g][ks][e] = tv[e];
        }

    // n weights -> LDS, per-lane-contiguous fragment order (8KB per wave slice)
    const int wnbase = wave * 4096 + lane * 8;
#pragma unroll
    for (int ks = 0; ks < 8; ks++)
        *(short8*)&wn[wnbase + ks * 512] =
            *(const short8*)(Whh + (size_t)(2 * HID + j) * HID + ks * 32 + quad * 8);

    for (int i = tid; i < 16 * HSTRIDE; i += 1024) hs[0][i] = 0;

    float hreg[4] = {};
    const float bhn = bhh[2 * HID + j];

    int gof[4], hof[4];
#pragma unroll
    for (int r = 0; r < 4; r++) {
        int row = (b0 + quad * 4 + r) * SEQT;
        gof[r] = row * G3 + j;
        hof[r] = row * HID + j;
    }
    const int abase = col * HSTRIDE + quad * 8;    // A-fragment read base (shorts)
    const int wbase = (quad * 4) * HSTRIDE + j;    // h write base (+r*HSTRIDE imm)

    // pipeline prologue: load gx for t=0
    float gA[3][4], gB[3][4];
#pragma unroll
    for (int r = 0; r < 4; r++) {
        gA[0][r] = gx[gof[r]];
        gA[1][r] = gx[gof[r] + HID];
        gA[2][r] = gx[gof[r] + 2 * HID];
    }
#pragma unroll
    for (int r = 0; r < 4; r++) gof[r] += G3;

    __syncthreads();

    auto step = [&](int t, float (&gc)[3][4], float (&gn)[3][4],
                    const unsigned short* hc, unsigned short* hn) {
        // pin r,z weight regs (opaque redefinition blocks rematerialization)
#pragma unroll
        for (int g = 0; g < 2; g++)
#pragma unroll
            for (int ks = 0; ks < 8; ks++)
#pragma unroll
                for (int e = 0; e < 4; e++)
                    asm volatile("" : "+v"(wrz[g][ks][e]));

        // issue next-step gx loads (consumed one full step later)
#pragma unroll
        for (int r = 0; r < 4; r++) {
            gn[0][r] = gx[gof[r]];
            gn[1][r] = gx[gof[r] + HID];
            gn[2][r] = gx[gof[r] + 2 * HID];
        }
#pragma unroll
        for (int r = 0; r < 4; r++) gof[r] += G3;

        f32x4 acc[3];
#pragma unroll
        for (int g = 0; g < 3; g++) acc[g] = (f32x4)(0.0f);

#pragma unroll
        for (int ks = 0; ks < 8; ks++) {
            short8 a = *(const short8*)(&hc[abase + ks * 32]);
            f32x4 w0v = { wrz[0][ks][0], wrz[0][ks][1], wrz[0][ks][2], wrz[0][ks][3] };
            f32x4 w1v = { wrz[1][ks][0], wrz[1][ks][1], wrz[1][ks][2], wrz[1][ks][3] };
            acc[0] = __builtin_amdgcn_mfma_f32_16x16x32_bf16(a, __builtin_bit_cast(short8, w0v), acc[0], 0, 0, 0);
            acc[1] = __builtin_amdgcn_mfma_f32_16x16x32_bf16(a, __builtin_bit_cast(short8, w1v), acc[1], 0, 0, 0);
            short8 bn = *(const short8*)&wn[wnbase + ks * 512];
            acc[2] = __builtin_amdgcn_mfma_f32_16x16x32_bf16(a, bn, acc[2], 0, 0, 0);
        }

        unsigned short hb[4];
#pragma unroll
        for (int r = 0; r < 4; r++) {
            // r,z: sigmoid(p) = 1/(1+exp2(-log2e*p)); gc holds -log2e*(gx+b)
            float er = exp2fast(__builtin_fmaf(acc[0][r], NLOG2E, gc[0][r]));
            float rr = __builtin_amdgcn_rcpf(1.0f + er);
            float ez = exp2fast(__builtin_fmaf(acc[1][r], NLOG2E, gc[1][r]));
            float zz = __builtin_amdgcn_rcpf(1.0f + ez);
            // n: tanh(p) = 1 - 2/(1+exp2(2*log2e*p)); gc[2] holds 2*log2e*(gx+bih_n)
            float inner = acc[2][r] + bhn;
            float en = exp2fast(__builtin_fmaf(rr * inner, LOG2E2, gc[2][r]));
            float nn = __builtin_fmaf(__builtin_amdgcn_rcpf(1.0f + en), -2.0f, 1.0f);
            float hnew = __builtin_fmaf(zz, hreg[r] - nn, nn);
            hreg[r] = hnew;
            hb[r] = f2bf(hnew);
            hn[wbase + r * HSTRIDE] = hb[r];
        }
        if (h1_out) {
#pragma unroll
            for (int r = 0; r < 4; r++) h1_out[hof[r]] = hb[r];
        }
#pragma unroll
        for (int r = 0; r < 4; r++) hof[r] += HID;

        if (hlast && t == SEQT - 1) {
#pragma unroll
            for (int r = 0; r < 4; r++)
                hlast[(b0 + quad * 4 + r) * HID + j] = hreg[r];
        }

        __syncthreads();
    };

    for (int t = 0; t < SEQT; t += 2) {
        step(t,     gA, gB, hs[0], hs[1]);
        step(t + 1, gB, gA, hs[1], hs[0]);
    }
}

// out[256,118] = hlast[256,256] @ fcW[118,256]^T + fcb
__global__ __launch_bounds__(128) void fc_kernel(
    const float* __restrict__ hlast, const float* __restrict__ W,
    const float* __restrict__ b, float* __restrict__ out)
{
    __shared__ float hsm[HID];
    int bidx = blockIdx.x;
    for (int i = threadIdx.x; i < HID; i += 128) hsm[i] = hlast[(size_t)bidx * HID + i];
    __syncthreads();
    int o = threadIdx.x;
    if (o < OUTD) {
        float acc = b[o];
        const float* wrow = W + (size_t)o * HID;
#pragma unroll 4
        for (int k = 0; k < HID; k++) acc += hsm[k] * wrow[k];
        out[(size_t)bidx * OUTD + o] = acc;
    }
}

extern "C" void kernel_launch(void* const* d_in, const int* in_sizes, int n_in,
                              void* d_out, int out_size, void* d_ws, size_t ws_size,
                              hipStream_t stream) {
    const float* x    = (const float*)d_in[0];
    const float* Wih0 = (const float*)d_in[1];
    const float* Whh0 = (const float*)d_in[2];
    const float* bih0 = (const float*)d_in[3];
    const float* bhh0 = (const float*)d_in[4];
    const float* Wih1 = (const float*)d_in[5];
    const float* Whh1 = (const float*)d_in[6];
    const float* bih1 = (const float*)d_in[7];
    const float* bhh1 = (const float*)d_in[8];
    const float* fcW  = (const float*)d_in[9];
    const float* fcb  = (const float*)d_in[10];
    float* out = (float*)d_out;

    char* ws = (char*)d_ws;
    size_t off = 0;
    auto walloc = [&](size_t bytes) {
        void* p = ws + off;
        off = (off + bytes + 255) & ~(size_t)255;
        return p;
    };

    const int M = BATCH * SEQT;                       // 51200
    float*          gxb  = (float*)         walloc((size_t)M * G3 * 4);   // 157.3 MB
    unsigned short* h1b  = (unsigned short*)walloc((size_t)M * HID * 2);  //  26.2 MB
    unsigned short* w0b  = (unsigned short*)walloc((size_t)W0SZ * 2);
    unsigned short* wh0b = (unsigned short*)walloc((size_t)WHSZ * 2);
    unsigned short* w1b  = (unsigned short*)walloc((size_t)WHSZ * 2);
    unsigned short* wh1b = (unsigned short*)walloc((size_t)WHSZ * 2);
    float*          bc0  = (float*)         walloc(G3 * 4);
    float*          bc1  = (float*)         walloc(G3 * 4);
    float*          hlast= (float*)         walloc((size_t)BATCH * HID * 4);

    cvt_weights <<<2688, 256, 0, stream>>>(Wih0, Whh0, Wih1, Whh1, w0b, wh0b, w1b, wh1b);
    combine_bias<<<6,    256, 0, stream>>>(bih0, bhh0, bih1, bhh1, bc0, bc1);

    // layer 0 (A = x, fp32 read + in-register cvt)
    gemm_bf16<IND, true ><<<M / 64, 256, 0, stream>>>(x, w0b, bc0, gxb);
    gru_scan<<<16, 1024, 0, stream>>>(gxb, wh0b, bhh0, h1b, nullptr);

    // layer 1
    gemm_bf16<HID, false><<<M / 64, 256, 0, stream>>>(h1b, w1b, bc1, gxb);
    gru_scan<<<16, 1024, 0, stream>>>(gxb, wh1b, bhh1, nullptr, hlast);

    fc_kernel<<<BATCH, 128, 0, stream>>>(hlast, fcW, fcb, out);
}

// Round 5
// 1104.314 us; speedup vs baseline: 2.1950x; 1.0671x over previous
//
#include <hip/hip_runtime.h>
#include <hip/hip_bf16.h>
#include <stdint.h>

// Problem constants
#define BATCH 256
#define SEQT  200
#define IND   128
#define HID   256
#define G3    768   // 3*HID
#define OUTD  118

#define HSTRIDE 264  // h-state LDS row stride in shorts (16B-aligned; 132 dw ≡ 4 mod 32)
#define W0SZ (G3*IND)
#define WHSZ (G3*HID)

#define LOG2E  1.44269504f
#define NLOG2E (-1.44269504f)
#define LOG2E2 2.88539008f

typedef short  short8 __attribute__((ext_vector_type(8)));
typedef float  f32x4  __attribute__((ext_vector_type(4)));
typedef int    i32x4  __attribute__((ext_vector_type(4)));

__device__ __forceinline__ float exp2fast(float x) {
#if __has_builtin(__builtin_amdgcn_exp2f)
    return __builtin_amdgcn_exp2f(x);
#else
    return exp2f(x);
#endif
}

__device__ __forceinline__ unsigned short f2bf(float x) {
    union { float f; uint32_t u; } v; v.f = x;
    uint32_t u = v.u;
    u += 0x7FFF + ((u >> 16) & 1);   // round-to-nearest-even
    return (unsigned short)(u >> 16);
}

// One fused conversion kernel for all four weight matrices.
__global__ void cvt_weights(const float* __restrict__ w0,  const float* __restrict__ wh0,
                            const float* __restrict__ w1,  const float* __restrict__ wh1,
                            unsigned short* __restrict__ o0,  unsigned short* __restrict__ oh0,
                            unsigned short* __restrict__ o1,  unsigned short* __restrict__ oh1) {
    int i = blockIdx.x * blockDim.x + threadIdx.x;
    const int n = W0SZ + 3 * WHSZ;
    int stride = gridDim.x * blockDim.x;
    for (; i < n; i += stride) {
        int j = i;
        if (j < W0SZ) { o0[j] = f2bf(w0[j]); continue; }
        j -= W0SZ;
        if (j < WHSZ) { oh0[j] = f2bf(wh0[j]); continue; }
        j -= WHSZ;
        if (j < WHSZ) { o1[j] = f2bf(w1[j]); continue; }
        j -= WHSZ;
        oh1[j] = f2bf(wh1[j]);
    }
}

// bc = bih + bhh for r,z gates (j < 512); bc = bih for n gate. Both layers.
__global__ void combine_bias(const float* __restrict__ bih0, const float* __restrict__ bhh0,
                             const float* __restrict__ bih1, const float* __restrict__ bhh1,
                             float* __restrict__ bc0, float* __restrict__ bc1) {
    int i = blockIdx.x * blockDim.x + threadIdx.x;
    if (i < G3) bc0[i] = bih0[i] + (i < 2 * HID ? bhh0[i] : 0.0f);
    else if (i < 2 * G3) {
        int j = i - G3;
        bc1[j] = bih1[j] + (j < 2 * HID ? bhh1[j] : 0.0f);
    }
}

// C[M,768] = scale[g] * (A[M,K] @ Bt[768,K]^T + bias[g])
// scale = -log2e (r,z) / +2*log2e (n): pre-scaled exp2 args for gru_scan.
template<int K, bool AF32>
__global__ __launch_bounds__(256) void gemm_bf16(
    const void* __restrict__ Av,
    const unsigned short* __restrict__ Bt,
    const float* __restrict__ bias,
    float* __restrict__ C)
{
    const int mt   = blockIdx.x;
    const int wave = threadIdx.x >> 6;
    const int lane = threadIdx.x & 63;
    const int col  = lane & 15;
    const int quad = lane >> 4;
    const int m0   = mt * 64 + wave * 16;
    constexpr int KS = K / 32;

    short8 a[KS];
    if constexpr (AF32) {
        const float* arow = (const float*)Av + (size_t)(m0 + col) * K;
#pragma unroll
        for (int ks = 0; ks < KS; ks++) {
            f32x4 lo = *(const f32x4*)(arow + ks * 32 + quad * 8);
            f32x4 hi = *(const f32x4*)(arow + ks * 32 + quad * 8 + 4);
#pragma unroll
            for (int e = 0; e < 4; e++) {
                a[ks][e]     = (short)f2bf(lo[e]);
                a[ks][e + 4] = (short)f2bf(hi[e]);
            }
        }
    } else {
        const unsigned short* arow = (const unsigned short*)Av + (size_t)(m0 + col) * K;
#pragma unroll
        for (int ks = 0; ks < KS; ks++)
            a[ks] = *(const short8*)(arow + ks * 32 + quad * 8);
    }

#pragma unroll
    for (int nb = 0; nb < 6; nb++) {
        const float scl = (nb < 4) ? NLOG2E : LOG2E2;
        f32x4 acc[8];
#pragma unroll
        for (int nt = 0; nt < 8; nt++) acc[nt] = (f32x4)(0.0f);
#pragma unroll
        for (int ks = 0; ks < KS; ks++) {
#pragma unroll
            for (int nt = 0; nt < 8; nt++) {
                const unsigned short* bp =
                    Bt + (size_t)(nb * 128 + nt * 16 + col) * K + ks * 32 + quad * 8;
                short8 b = *(const short8*)bp;
                acc[nt] = __builtin_amdgcn_mfma_f32_16x16x32_bf16(a[ks], b, acc[nt], 0, 0, 0);
            }
        }
#pragma unroll
        for (int nt = 0; nt < 8; nt++) {
            int g = nb * 128 + nt * 16 + col;
            float bia = bias[g];
#pragma unroll
            for (int r = 0; r < 4; r++) {
                int m = m0 + quad * 4 + r;
                C[(size_t)m * G3 + g] = (acc[nt][r] + bia) * scl;
            }
        }
    }
}

// GRU scan. 16 WGs x 512 threads (8 waves, 2/SIMD @ 256-reg budget).
// WG owns batches [wg*16,+16); wave owns 32 j-cols (jt0/jt1) x 3 gates.
// In registers (pinned): r,z weights both jt (128 regs) + n-gate jt0 (32 regs).
// In LDS: n-gate jt1 weights (64KB) + double-buffered bf16 h (2x8.3KB).
// Per-step LDS reads: 8 waves x (8 h + 8 wn1) b128 = 128 ops (half of round 4).
__global__ __launch_bounds__(512, 2) void gru_scan(
    const float* __restrict__ gx,            // [B*T,768] pre-scaled exp2 args
    const unsigned short* __restrict__ Whh,  // [768,256] bf16
    const float* __restrict__ bhh,           // [768] (only n-part used)
    unsigned short* __restrict__ h1_out,     // [B*T,256] bf16 or nullptr
    float* __restrict__ hlast)               // [B,256] fp32 or nullptr
{
    __shared__ unsigned short hs[2][16 * HSTRIDE];   // 16,896 B
    __shared__ unsigned short wn1[8 * 8 * 512];      // 65,536 B (n-gate jt1)

    const int b0    = blockIdx.x * 16;
    const int tid   = threadIdx.x;
    const int wave  = tid >> 6;
    const int lane  = tid & 63;
    const int col   = lane & 15;
    const int quad  = lane >> 4;
    const int jbase = wave * 32;
    const int j0    = jbase + col;        // jt0 column
    const int j1    = jbase + 16 + col;   // jt1 column

    // r,z weights (both jt) -> pinned registers: 128 VGPRs
    i32x4 wrz[2][2][8];   // [gate][jt][ks]
#pragma unroll
    for (int g = 0; g < 2; g++)
#pragma unroll
        for (int jt = 0; jt < 2; jt++)
#pragma unroll
            for (int ks = 0; ks < 8; ks++)
                wrz[g][jt][ks] = *(const i32x4*)(
                    Whh + (size_t)(g * HID + jbase + jt * 16 + col) * HID + ks * 32 + quad * 8);

    // n-gate jt0 -> pinned registers: 32 VGPRs
    i32x4 wn0[8];
#pragma unroll
    for (int ks = 0; ks < 8; ks++)
        wn0[ks] = *(const i32x4*)(
            Whh + (size_t)(2 * HID + j0) * HID + ks * 32 + quad * 8);

    // n-gate jt1 -> LDS, per-lane-contiguous fragment order (conflict-free)
    const int wnbase = wave * 4096 + lane * 8;   // shorts
#pragma unroll
    for (int ks = 0; ks < 8; ks++)
        *(short8*)&wn1[wnbase + ks * 512] =
            *(const short8*)(Whh + (size_t)(2 * HID + j1) * HID + ks * 32 + quad * 8);

    for (int i = tid; i < 16 * HSTRIDE; i += 512) hs[0][i] = 0;

    float hreg[2][4] = {};
    float bhn[2] = { bhh[2 * HID + j0], bhh[2 * HID + j1] };

    int gof[4], hof[4];
#pragma unroll
    for (int r = 0; r < 4; r++) {
        int row = (b0 + quad * 4 + r) * SEQT;
        gof[r] = row * G3 + j0;
        hof[r] = row * HID + j0;
    }
    const int abase = col * HSTRIDE + quad * 8;          // A-frag read base (shorts)
    const int wbase = (quad * 4) * HSTRIDE + j0;         // h write base

    __syncthreads();

    for (int t = 0; t < SEQT; t++) {
        const unsigned short* hc = hs[t & 1];
        unsigned short*       hn = hs[(t & 1) ^ 1];

        // pin weight regs: opaque per-iter redefinition blocks remat/sinking
#pragma unroll
        for (int g = 0; g < 2; g++)
#pragma unroll
            for (int jt = 0; jt < 2; jt++)
#pragma unroll
                for (int ks = 0; ks < 8; ks++)
                    asm volatile("" : "+v"(wrz[g][jt][ks]));
#pragma unroll
        for (int ks = 0; ks < 8; ks++)
            asm volatile("" : "+v"(wn0[ks]));

        // gx loads at step top; consumed ~1.5k cycles later in the gate phase
        float gc[3][2][4];   // [gate][jt][r]
#pragma unroll
        for (int r = 0; r < 4; r++)
#pragma unroll
            for (int g3 = 0; g3 < 3; g3++) {
                gc[g3][0][r] = gx[gof[r] + g3 * HID];
                gc[g3][1][r] = gx[gof[r] + g3 * HID + 16];
            }
#pragma unroll
        for (int r = 0; r < 4; r++) gof[r] += G3;

        f32x4 acc[3][2];
#pragma unroll
        for (int g = 0; g < 3; g++)
#pragma unroll
            for (int jt = 0; jt < 2; jt++) acc[g][jt] = (f32x4)(0.0f);

#pragma unroll
        for (int ks = 0; ks < 8; ks++) {
            short8 a = *(const short8*)(&hc[abase + ks * 32]);
            acc[0][0] = __builtin_amdgcn_mfma_f32_16x16x32_bf16(a, __builtin_bit_cast(short8, wrz[0][0][ks]), acc[0][0], 0, 0, 0);
            acc[0][1] = __builtin_amdgcn_mfma_f32_16x16x32_bf16(a, __builtin_bit_cast(short8, wrz[0][1][ks]), acc[0][1], 0, 0, 0);
            acc[1][0] = __builtin_amdgcn_mfma_f32_16x16x32_bf16(a, __builtin_bit_cast(short8, wrz[1][0][ks]), acc[1][0], 0, 0, 0);
            acc[1][1] = __builtin_amdgcn_mfma_f32_16x16x32_bf16(a, __builtin_bit_cast(short8, wrz[1][1][ks]), acc[1][1], 0, 0, 0);
            acc[2][0] = __builtin_amdgcn_mfma_f32_16x16x32_bf16(a, __builtin_bit_cast(short8, wn0[ks]),       acc[2][0], 0, 0, 0);
            short8 b1 = *(const short8*)&wn1[wnbase + ks * 512];
            acc[2][1] = __builtin_amdgcn_mfma_f32_16x16x32_bf16(a, b1, acc[2][1], 0, 0, 0);
        }

        unsigned short hb[2][4];
#pragma unroll
        for (int jt = 0; jt < 2; jt++)
#pragma unroll
            for (int r = 0; r < 4; r++) {
                // sigmoid(p) = 1/(1+exp2(-log2e*p)); gc holds -log2e*(gx+b)
                float er = exp2fast(__builtin_fmaf(acc[0][jt][r], NLOG2E, gc[0][jt][r]));
                float rr = __builtin_amdgcn_rcpf(1.0f + er);
                float ez = exp2fast(__builtin_fmaf(acc[1][jt][r], NLOG2E, gc[1][jt][r]));
                float zz = __builtin_amdgcn_rcpf(1.0f + ez);
                // tanh(p) = 1 - 2/(1+exp2(2*log2e*p)); gc[2] holds 2*log2e*(gx+bih_n)
                float inner = acc[2][jt][r] + bhn[jt];
                float en = exp2fast(__builtin_fmaf(rr * inner, LOG2E2, gc[2][jt][r]));
                float nn = __builtin_fmaf(__builtin_amdgcn_rcpf(1.0f + en), -2.0f, 1.0f);
                float hnew = __builtin_fmaf(zz, hreg[jt][r] - nn, nn);
                hreg[jt][r] = hnew;
                hb[jt][r] = f2bf(hnew);
                hn[wbase + r * HSTRIDE + jt * 16] = hb[jt][r];
            }

        if (h1_out) {
#pragma unroll
            for (int jt = 0; jt < 2; jt++)
#pragma unroll
                for (int r = 0; r < 4; r++)
                    h1_out[hof[r] + jt * 16] = hb[jt][r];
        }
#pragma unroll
        for (int r = 0; r < 4; r++) hof[r] += HID;

        if (hlast && t == SEQT - 1) {
#pragma unroll
            for (int jt = 0; jt < 2; jt++)
#pragma unroll
                for (int r = 0; r < 4; r++)
                    hlast[(b0 + quad * 4 + r) * HID + j0 + jt * 16] = hreg[jt][r];
        }

        __syncthreads();
    }
}

// out[256,118] = hlast[256,256] @ fcW[118,256]^T + fcb
__global__ __launch_bounds__(128) void fc_kernel(
    const float* __restrict__ hlast, const float* __restrict__ W,
    const float* __restrict__ b, float* __restrict__ out)
{
    __shared__ float hsm[HID];
    int bidx = blockIdx.x;
    for (int i = threadIdx.x; i < HID; i += 128) hsm[i] = hlast[(size_t)bidx * HID + i];
    __syncthreads();
    int o = threadIdx.x;
    if (o < OUTD) {
        float acc = b[o];
        const float* wrow = W + (size_t)o * HID;
#pragma unroll 4
        for (int k = 0; k < HID; k++) acc += hsm[k] * wrow[k];
        out[(size_t)bidx * OUTD + o] = acc;
    }
}

extern "C" void kernel_launch(void* const* d_in, const int* in_sizes, int n_in,
                              void* d_out, int out_size, void* d_ws, size_t ws_size,
                              hipStream_t stream) {
    const float* x    = (const float*)d_in[0];
    const float* Wih0 = (const float*)d_in[1];
    const float* Whh0 = (const float*)d_in[2];
    const float* bih0 = (const float*)d_in[3];
    const float* bhh0 = (const float*)d_in[4];
    const float* Wih1 = (const float*)d_in[5];
    const float* Whh1 = (const float*)d_in[6];
    const float* bih1 = (const float*)d_in[7];
    const float* bhh1 = (const float*)d_in[8];
    const float* fcW  = (const float*)d_in[9];
    const float* fcb  = (const float*)d_in[10];
    float* out = (float*)d_out;

    char* ws = (char*)d_ws;
    size_t off = 0;
    auto walloc = [&](size_t bytes) {
        void* p = ws + off;
        off = (off + bytes + 255) & ~(size_t)255;
        return p;
    };

    const int M = BATCH * SEQT;                       // 51200
    float*          gxb  = (float*)         walloc((size_t)M * G3 * 4);   // 157.3 MB
    unsigned short* h1b  = (unsigned short*)walloc((size_t)M * HID * 2);  //  26.2 MB
    unsigned short* w0b  = (unsigned short*)walloc((size_t)W0SZ * 2);
    unsigned short* wh0b = (unsigned short*)walloc((size_t)WHSZ * 2);
    unsigned short* w1b  = (unsigned short*)walloc((size_t)WHSZ * 2);
    unsigned short* wh1b = (unsigned short*)walloc((size_t)WHSZ * 2);
    float*          bc0  = (float*)         walloc(G3 * 4);
    float*          bc1  = (float*)         walloc(G3 * 4);
    float*          hlast= (float*)         walloc((size_t)BATCH * HID * 4);

    cvt_weights <<<2688, 256, 0, stream>>>(Wih0, Whh0, Wih1, Whh1, w0b, wh0b, w1b, wh1b);
    combine_bias<<<6,    256, 0, stream>>>(bih0, bhh0, bih1, bhh1, bc0, bc1);

    // layer 0 (A = x, fp32 read + in-register cvt)
    gemm_bf16<IND, true ><<<M / 64, 256, 0, stream>>>(x, w0b, bc0, gxb);
    gru_scan<<<16, 512, 0, stream>>>(gxb, wh0b, bhh0, h1b, nullptr);

    // layer 1
    gemm_bf16<HID, false><<<M / 64, 256, 0, stream>>>(h1b, w1b, bc1, gxb);
    gru_scan<<<16, 512, 0, stream>>>(gxb, wh1b, bhh1, nullptr, hlast);

    fc_kernel<<<BATCH, 128, 0, stream>>>(hlast, fcW, fcb, out);
}